// Round 6
// baseline (207.315 us; speedup 1.0000x reference)
//
#include <hip/hip_runtime.h>
#include <math.h>

// Problem constants (match reference setup_inputs)
constexpr int B = 16;
constexpr int N = 4096;
constexpr int D = 512;
constexpr int R = 64;
constexpr int K = 128;

constexpr int C     = 16;         // chunks per batch -> 256 stream blocks (1/CU)
constexpr int NC    = N / C;      // 256 rows per chunk
constexpr int ST    = 32;         // subtile rows staged per step (64 KB buffer)
constexpr int NSUB  = NC / ST;    // 8 subtiles per chunk
constexpr int SLOTS = 32;         // per-(r,ch) bucket cap; mean 8, P(>32) ~ 3e-11

// Workspace layout (byte offsets). Fully rewritten each launch (poison-safe).
constexpr size_t OFF_LP   = 0;              // B*R*C f32   (64 KiB)
constexpr size_t OFF_PART = 1024 * 1024;    // B*R*C*D f32 (32 MiB)

__device__ __forceinline__ float dot4(const float4 a, const float4 b) {
    return a.x * b.x + a.y * b.y + a.z * b.z + a.w * b.w;
}

// ---------------------------------------------------------------------------
// Streaming scatter pass: block = (b, chunk). Reads its 256 rows of x exactly
// once (coalesced, reg-staged double-buffered LDS subtiles of ST=32 rows,
// ONE barrier per subtile). In-block inverted index built from idx while
// subtile-0 loads are in flight.
//
// Scores are computed ONCE per row, during staging, from the in-register
// fragments: thread tid holds elem (tid&127) of rows {tid>>7,+8,+16,+24}, so
// partial dots vs wf = W4[tid&127] + 4 independent butterflies (pipelined,
// hidden under the vmcnt drain) yield per-64-elem half-sums in s_pp[buf][row].
// The per-hit work is then ds_read_b64 + add + exp + 2x ds_read_b128 + 8 FMA
// — no serial shuffle chain, so the barrier-coupled straggler tax that
// dominated round 4 is gone. Accumulation stays in registers (4 regions/wave,
// no atomics). No max-subtraction: s ~ N(0,1), |s| < 6 over 65K draws,
// fp32-safe (validated passing rounds 1-4).
// ---------------------------------------------------------------------------
__global__ __launch_bounds__(1024, 4) void stream_accum(
    const float* __restrict__ x,     // [B, N, D]
    const int*   __restrict__ idx,   // [R, K]
    const float* __restrict__ W,     // [D]
    float* __restrict__ part,        // [B, R, C, D] unnormalized partials
    float* __restrict__ lp)          // [B, R, C]    partial denominators
{
    extern __shared__ float smem[];            // 2 * ST * D floats (128 KiB)
    __shared__ int   s_cnt[R];                 // per-region occurrence count
    __shared__ int   s_ents[R][SLOTS];         // local row per occurrence
    __shared__ float s_pp[2][ST][2];           // per-row score half-sums

    const int b  = blockIdx.x >> 4;
    const int ch = blockIdx.x & 15;

    const int tid  = threadIdx.x;
    const int lane = tid & 63;
    const int wave = tid >> 6;                 // 0..15

    const float4* W4 = (const float4*)W;
    const float4 w0 = W4[lane];
    const float4 w1 = W4[lane + 64];
    const float4 wf = (wave & 1) ? w1 : w0;    // = W4[tid & 127]

    const float* xb = x + ((size_t)b * N + (size_t)ch * NC) * D;

    // Issue subtile-0 global loads FIRST; latency hides under the index build.
    const float4* src0 = (const float4*)xb;
    float4 r0 = src0[tid],        r1 = src0[tid + 1024],
           r2 = src0[tid + 2048], r3 = src0[tid + 3072];

    if (tid < R) s_cnt[tid] = 0;
    __syncthreads();

    // In-block inverted index for THIS chunk (one entry per occurrence ->
    // duplicates handled exactly like the reference).
    #pragma unroll
    for (int i = 0; i < (R * K) / 1024; ++i) {
        const int e = i * 1024 + tid;
        const int n = idx[e];
        if ((n >> 8) == ch) {                  // NC = 256
            const int r = e >> 7;              // region = e / K
            const int s = atomicAdd(&s_cnt[r], 1);   // native int LDS atomic
            if (s < SLOTS) s_ents[r][s] = n & (NC - 1);
        }
    }

    // Stage subtile 0 + compute its row-score half-sums from registers.
    {
        float4* buf0 = (float4*)smem;
        buf0[tid] = r0; buf0[tid + 1024] = r1;
        buf0[tid + 2048] = r2; buf0[tid + 3072] = r3;
        float p0 = dot4(r0, wf), p1 = dot4(r1, wf),
              p2 = dot4(r2, wf), p3 = dot4(r3, wf);
        #pragma unroll
        for (int off = 1; off < 64; off <<= 1) {   // 4 independent chains
            p0 += __shfl_xor(p0, off, 64); p1 += __shfl_xor(p1, off, 64);
            p2 += __shfl_xor(p2, off, 64); p3 += __shfl_xor(p3, off, 64);
        }
        if (lane == 0) {
            const int rb = wave >> 1, hf = wave & 1;
            s_pp[0][rb][hf]      = p0;  s_pp[0][rb + 8][hf]  = p1;
            s_pp[0][rb + 16][hf] = p2;  s_pp[0][rb + 24][hf] = p3;
        }
    }
    __syncthreads();     // index + subtile-0 data + subtile-0 scores ready

    // Per-lane bucket entries for this wave's 4 regions (sentinel = big).
    int entv[4];
    #pragma unroll
    for (int rr = 0; rr < 4; ++rr) {
        const int r  = 4 * wave + rr;
        const int cb = min(s_cnt[r], SLOTS);
        entv[rr] = (lane < cb) ? s_ents[r][lane] : 0x7fffffff;
    }

    float4 acc0[4], acc1[4];
    float  lsum[4];
    #pragma unroll
    for (int rr = 0; rr < 4; ++rr) {
        acc0[rr] = make_float4(0.f, 0.f, 0.f, 0.f);
        acc1[rr] = make_float4(0.f, 0.f, 0.f, 0.f);
        lsum[rr] = 0.f;
    }

    for (int t = 0; t < NSUB; ++t) {
        const int cur = t & 1;
        float4* buf = (float4*)(smem + cur * ST * D);
        const bool have = (t + 1 < NSUB);

        // Issue next subtile's loads at the top (T14 issue-early).
        if (have) {
            const float4* src = (const float4*)(xb + (size_t)(t + 1) * ST * D);
            r0 = src[tid];        r1 = src[tid + 1024];
            r2 = src[tid + 2048]; r3 = src[tid + 3072];
        }

        // Hits for this wave's regions; e from precomputed half-sums.
        const int t0 = t * ST;
        #pragma unroll
        for (int rr = 0; rr < 4; ++rr) {
            unsigned long long hits =
                __ballot(entv[rr] >= t0 && entv[rr] < t0 + ST);
            while (hits) {
                const int j  = (int)__builtin_ctzll(hits); hits &= hits - 1;
                const int lr = __shfl(entv[rr], j, 64) - t0;  // wave-uniform
                const float2 ph = *(const float2*)&s_pp[cur][lr][0];
                const float  e  = __expf(ph.x + ph.y);
                const float4 u0 = buf[lr * 128 + lane];
                const float4 u1 = buf[lr * 128 + 64 + lane];
                acc0[rr].x += e * u0.x; acc0[rr].y += e * u0.y;
                acc0[rr].z += e * u0.z; acc0[rr].w += e * u0.w;
                acc1[rr].x += e * u1.x; acc1[rr].y += e * u1.y;
                acc1[rr].z += e * u1.z; acc1[rr].w += e * u1.w;
                lsum[rr] += e;
            }
        }

        // Write-late: stage next subtile + its scores, ONE barrier.
        // Writing buf[nxt]/s_pp[nxt] is safe: last read at t-1, fenced by the
        // barrier at the end of t-1.
        if (have) {
            const int nxt = 1 - cur;
            float4* nb = (float4*)(smem + nxt * ST * D);
            nb[tid] = r0; nb[tid + 1024] = r1;
            nb[tid + 2048] = r2; nb[tid + 3072] = r3;
            float p0 = dot4(r0, wf), p1 = dot4(r1, wf),
                  p2 = dot4(r2, wf), p3 = dot4(r3, wf);
            #pragma unroll
            for (int off = 1; off < 64; off <<= 1) {
                p0 += __shfl_xor(p0, off, 64); p1 += __shfl_xor(p1, off, 64);
                p2 += __shfl_xor(p2, off, 64); p3 += __shfl_xor(p3, off, 64);
            }
            if (lane == 0) {
                const int rb = wave >> 1, hf = wave & 1;
                s_pp[nxt][rb][hf]      = p0;  s_pp[nxt][rb + 8][hf]  = p1;
                s_pp[nxt][rb + 16][hf] = p2;  s_pp[nxt][rb + 24][hf] = p3;
            }
            __syncthreads();
        }
    }

    // Epilogue: coalesced partial writes; no cross-wave reduction needed.
    #pragma unroll
    for (int rr = 0; rr < 4; ++rr) {
        const int region = 4 * wave + rr;
        float* pb = part + ((size_t)(b * R + region) * C + ch) * D;
        ((float4*)pb)[lane]      = acc0[rr];
        ((float4*)pb)[lane + 64] = acc1[rr];
        if (lane == 0) lp[(b * R + region) * C + ch] = lsum[rr];
    }
}

// ---------------------------------------------------------------------------
// Combine: block per (b,r); thread d sums 16 chunk partials (L2/L3-warm,
// coalesced 2 KB runs) and normalizes.
// ---------------------------------------------------------------------------
__global__ __launch_bounds__(512, 8) void combine(
    const float* __restrict__ part,  // [B, R, C, D]
    const float* __restrict__ lp,    // [B, R, C]
    float* __restrict__ out)         // [B, R, D]
{
    const int br = blockIdx.x;       // b*R + r
    const int d  = threadIdx.x;

    float lsum = 0.f;
    #pragma unroll
    for (int c = 0; c < C; ++c) lsum += lp[br * C + c];

    float sum = 0.f;
    #pragma unroll
    for (int c = 0; c < C; ++c)
        sum += part[((size_t)br * C + c) * D + d];

    out[(size_t)br * D + d] = sum / lsum;
}

extern "C" void kernel_launch(void* const* d_in, const int* in_sizes, int n_in,
                              void* d_out, int out_size, void* d_ws, size_t ws_size,
                              hipStream_t stream) {
    const float* x   = (const float*)d_in[0];   // [B,N,D] fp32
    const int*   idx = (const int*)d_in[1];     // [R,K] int32
    const float* W   = (const float*)d_in[2];   // [1,D] fp32
    // d_in[3] = bias, uniform across scores -> cancels in softmax
    float* out = (float*)d_out;                 // [B,R,D] fp32

    char* ws = (char*)d_ws;
    float* lp   = (float*)(ws + OFF_LP);
    float* part = (float*)(ws + OFF_PART);

    constexpr int LDS_BYTES = 2 * ST * D * 4;   // 131072 B dynamic
    static bool attr_set = false;
    if (!attr_set) {
        hipFuncSetAttribute(reinterpret_cast<const void*>(stream_accum),
                            hipFuncAttributeMaxDynamicSharedMemorySize, LDS_BYTES);
        attr_set = true;
    }

    stream_accum<<<B * C, 1024, LDS_BYTES, stream>>>(x, idx, W, part, lp);
    combine     <<<B * R, 512,  0,         stream>>>(part, lp, out);
}

// Round 7
// 196.784 us; speedup vs baseline: 1.0535x; 1.0535x over previous
//
#include <hip/hip_runtime.h>
#include <math.h>

// Problem constants (match reference setup_inputs)
constexpr int B = 16;
constexpr int N = 4096;
constexpr int D = 512;
constexpr int R = 64;
constexpr int K = 128;
constexpr int WAVES = 8;          // 512-thread blocks -> 32 waves/CU at 4 blocks/CU
constexpr int KPW = K / WAVES;    // 16 rows per wave

// One 512-thread block per (b, r). Fused single-pass with per-wave online
// softmax: each wave owns 16 rows; each gathered row is read from global
// exactly once (2x float4 per lane), used for both score and accumulation.
// 8-wave split-softmax combine in the epilogue.
// Bias b[0] is uniform across scores -> cancels in softmax; omitted.
//
// Verified best configuration (195.9 us total). Kernel time ~40 us =
// 256 MiB gather at 6.4 TB/s vs 6.9 TB/s measured ceiling (fill kernel).
// R1 proved the loop is BW-bound, not dependency-bound (decoupling all
// serial softmax work left accum time unchanged); R2-R6 proved the
// byte-reducing scatter family pays more in partials round-trip + lower
// occupancy than it saves in x bytes (L3 serves the 2x row reuse at
// near-HBM rate, so re-reads are nearly free).
__global__ __launch_bounds__(512, 8) void regional_attn_fused(
    const float* __restrict__ x,     // [B, N, D]
    const int*   __restrict__ idx,   // [R, K]
    const float* __restrict__ W,     // [D]
    float* __restrict__ out)         // [B, R, D]
{
    // XCD swizzle: blocks are dispatched round-robin over 8 XCDs by
    // blockIdx. Map so XCD j gets b in {2j, 2j+1}: shrinks per-XCD L2
    // working set and keeps all row reuse for a given b on one XCD.
    const int v    = blockIdx.x;          // 0..1023
    const int xcd  = v & 7;
    const int slot = v >> 3;              // 0..127
    const int b    = xcd * 2 + (slot >> 6);
    const int r    = slot & 63;

    const int tid  = threadIdx.x;
    const int lane = tid & 63;
    const int wave = tid >> 6;            // 0..7

    __shared__ int   s_idx[K];
    __shared__ float s_O[WAVES][D];       // 16 KB partial outputs
    __shared__ float s_m[WAVES];
    __shared__ float s_l[WAVES];

    if (tid < K) s_idx[tid] = idx[r * K + tid];

    // W fragment: lane holds d in [4*lane, 4*lane+4) and [256+4*lane, ...)
    const float4* W4 = (const float4*)W;
    const float4  w0 = W4[lane];
    const float4  w1 = W4[lane + 64];

    __syncthreads();

    const float* xb = x + (size_t)b * N * D;
    const int kbase = wave * KPW;

    float  m = -INFINITY;
    float  l = 0.0f;
    float4 O0 = make_float4(0.f, 0.f, 0.f, 0.f);
    float4 O1 = make_float4(0.f, 0.f, 0.f, 0.f);

    // depth-1 software prefetch: load row kk+1 while processing row kk
    const float4* row = (const float4*)(xb + (size_t)s_idx[kbase] * D);
    float4 a0 = row[lane];
    float4 a1 = row[lane + 64];

    #pragma unroll 2
    for (int kk = 0; kk < KPW; ++kk) {
        float4 b0 = a0, b1 = a1;
        if (kk + 1 < KPW) {
            const float4* nrow = (const float4*)(xb + (size_t)s_idx[kbase + kk + 1] * D);
            a0 = nrow[lane];
            a1 = nrow[lane + 64];
        }
        // score = dot(row, W): 8 partials per lane, butterfly so all lanes get p
        float p = b0.x * w0.x + b0.y * w0.y + b0.z * w0.z + b0.w * w0.w
                + b1.x * w1.x + b1.y * w1.y + b1.z * w1.z + b1.w * w1.w;
        #pragma unroll
        for (int off = 1; off < 64; off <<= 1)
            p += __shfl_xor(p, off, 64);
        // online softmax update (wave-uniform p, m, l, alpha)
        float m_new  = fmaxf(m, p);
        float alpha  = __expf(m - m_new);     // exp(-inf)=0 handles first iter
        float e      = __expf(p - m_new);
        m = m_new;
        l = l * alpha + e;
        O0.x = O0.x * alpha + e * b0.x;
        O0.y = O0.y * alpha + e * b0.y;
        O0.z = O0.z * alpha + e * b0.z;
        O0.w = O0.w * alpha + e * b0.w;
        O1.x = O1.x * alpha + e * b1.x;
        O1.y = O1.y * alpha + e * b1.y;
        O1.z = O1.z * alpha + e * b1.z;
        O1.w = O1.w * alpha + e * b1.w;
    }

    // stash per-wave state
    ((float4*)&s_O[wave][0])[lane]      = O0;
    ((float4*)&s_O[wave][0])[lane + 64] = O1;
    if (lane == 0) { s_m[wave] = m; s_l[wave] = l; }
    __syncthreads();

    // combine 8 waves: out = sum_w O_w*exp(m_w-M) / sum_w l_w*exp(m_w-M)
    float M = s_m[0];
    #pragma unroll
    for (int w = 1; w < WAVES; ++w) M = fmaxf(M, s_m[w]);
    float ew[WAVES];
    float denom = 0.0f;
    #pragma unroll
    for (int w = 0; w < WAVES; ++w) {
        ew[w] = __expf(s_m[w] - M);
        denom += s_l[w] * ew[w];
    }
    const float inv = 1.0f / denom;

    const int d = tid;   // each thread owns one output element
    float o = 0.0f;
    #pragma unroll
    for (int w = 0; w < WAVES; ++w) o += s_O[w][d] * ew[w];

    out[((size_t)b * R + r) * D + d] = o * inv;
}

extern "C" void kernel_launch(void* const* d_in, const int* in_sizes, int n_in,
                              void* d_out, int out_size, void* d_ws, size_t ws_size,
                              hipStream_t stream) {
    const float* x    = (const float*)d_in[0];  // [B,N,D] fp32
    const int*   idx  = (const int*)d_in[1];    // [R,K] int32
    const float* W    = (const float*)d_in[2];  // [1,D] fp32
    // d_in[3] = bias, cancels in softmax
    float* out = (float*)d_out;                 // [B,R,D] fp32

    dim3 grid(B * R);
    dim3 block(512);
    regional_attn_fused<<<grid, block, 0, stream>>>(x, idx, W, out);
}